// Round 15
// baseline (551.338 us; speedup 1.0000x reference)
//
#include <hip/hip_runtime.h>

typedef float f32x4 __attribute__((ext_vector_type(4)));
typedef __bf16 bf16x8 __attribute__((ext_vector_type(8)));
typedef _Float16 f16x8 __attribute__((ext_vector_type(8)));
typedef short s16x8 __attribute__((ext_vector_type(8)));
typedef unsigned int u32x4 __attribute__((ext_vector_type(4)));
typedef unsigned short u16;

#define DEV static __device__ __forceinline__

#define SEL_BAND 2.0e-3f   // fp16-GEMM1 error band for exact re-ranking

DEV u16 f2bf_rn(float f) {
    unsigned u = __float_as_uint(f);
    return (u16)((u + 0x7fffu + ((u >> 16) & 1u)) >> 16);
}

typedef __attribute__((address_space(3))) unsigned int lds_u32;
typedef __attribute__((address_space(1))) const unsigned int glb_u32;

DEV void gload16(const void* g, void* l) {
    __builtin_amdgcn_global_load_lds((glb_u32*)g, (lds_u32*)l, 16, 0, 0);
}
DEV void bar_raw() { asm volatile("s_barrier" ::: "memory"); }
DEV void wait_vm4() { asm volatile("s_waitcnt vmcnt(4)" ::: "memory"); }
DEV void wait_vm0() { asm volatile("s_waitcnt vmcnt(0)" ::: "memory"); }

// ---------------- transpose [R][C] f32 -> [C][R] fp16*256 + f32 ----------------
__global__ __launch_bounds__(256) void tr_hf(const float* __restrict__ src, int R, int C,
                                             u16* __restrict__ hT, float* __restrict__ fT) {
    __shared__ float t[32][33];
    int tx = threadIdx.x, ty = threadIdx.y;
    int c0 = blockIdx.x * 32, r0 = blockIdx.y * 32;
#pragma unroll
    for (int i = 0; i < 4; i++) t[ty + i * 8][tx] = src[(size_t)(r0 + ty + i * 8) * C + c0 + tx];
    __syncthreads();
#pragma unroll
    for (int i = 0; i < 4; i++) {
        int c = c0 + ty + i * 8;
        float v = t[tx][ty + i * 8];
        size_t o = (size_t)c * R + r0 + tx;
        hT[o] = __builtin_bit_cast(u16, (_Float16)(v * 256.0f));
        fT[o] = v;
    }
}

// ---------------- transpose [R][C] f32 -> [C][R] bf16 ----------------
__global__ __launch_bounds__(256) void tr_bf16(const float* __restrict__ src, int R, int C,
                                               u16* __restrict__ dst) {
    __shared__ float t[32][33];
    int tx = threadIdx.x, ty = threadIdx.y;
    int c0 = blockIdx.x * 32, r0 = blockIdx.y * 32;
#pragma unroll
    for (int i = 0; i < 4; i++) t[ty + i * 8][tx] = src[(size_t)(r0 + ty + i * 8) * C + c0 + tx];
    __syncthreads();
#pragma unroll
    for (int i = 0; i < 4; i++)
        dst[(size_t)(c0 + ty + i * 8) * R + r0 + tx] = f2bf_rn(t[tx][ty + i * 8]);
}

// ---------------- GEMM1: 128x256, 8 waves, split-K, K_STEP=32, 2-buf 64KB, R12 schedule ----------------
// Per tile: {wait_vm4 (own stage(t) landed); bar; compute buf[t&1]; bar; stage(t+2->buf[t&1])}.
// RAW: every wave certifies its OWN loads BEFORE the barrier -> after barrier whole buffer valid.
// WAR: stage(t+2) overwrites buf last read in compute(t), finished before the second barrier.
template <int SPLITK>
__global__ __launch_bounds__(512) void gemm1_k(const float* __restrict__ A,
                                               const u16* __restrict__ BT,
                                               const float* __restrict__ bias,
                                               float* __restrict__ Out,
                                               int M, int N, int K) {
    constexpr int ABYT = 128 * 32 * 4;   // 16 KB f32
    constexpr int BBYT = 256 * 32 * 2;   // 16 KB f16 bits
    constexpr int STR = ABYT + BBYT;     // 32 KB
    __shared__ __align__(16) char lds[2 * STR];   // 64 KB -> 2 blocks/CU
    int tid = threadIdx.x, lane = tid & 63, wid = tid >> 6;
    int wr = wid >> 2, wc = wid & 3;    // 2 x 4 waves, WM=64, WN=64

    int lin = blockIdx.x + gridDim.x * (blockIdx.y + gridDim.y * blockIdx.z);
    int nwg = gridDim.x * gridDim.y * gridDim.z;
    int q = nwg >> 3;
    int logical = (lin & 7) * q + (lin >> 3);
    int Ny = N >> 8, Mx = M >> 7;
    int per = Mx * Ny;
    int z = logical / per;
    int rem = logical - z * per;
    int mb = rem / Ny, nb = rem - mb * Ny;   // nb fastest
    int m0 = mb << 7, n0 = nb << 8;
    int Ksl = K / SPLITK;
    int kbase = z * Ksl;
    int NT = Ksl >> 5;

    auto stage = [&](int t, int c) {
        int k0 = kbase + (t << 5);
        char* bA = lds + c * STR;
        char* bB = bA + ABYT;
#pragma unroll
        for (int i = 0; i < 2; i++) {    // A: 128 rows x 8 f32-granules
            int s = i * 512 + tid;
            int r = s >> 3, g = s & 7;
            int gs = (g ^ r) & 7;
            gload16(A + (size_t)(m0 + r) * K + k0 + gs * 4, bA + r * 128 + g * 16);
        }
#pragma unroll
        for (int i = 0; i < 2; i++) {    // B: 256 rows x 4 half-granules
            int s = i * 512 + tid;
            int r = s >> 2, g = s & 3;
            int gs = (g ^ (r >> 1)) & 3;
            gload16(BT + (size_t)(n0 + r) * K + k0 + gs * 8, bB + r * 64 + g * 16);
        }
    };

    f32x4 acc[4][4] = {};
    stage(0, 0);
    if (NT > 1) stage(1, 1);
    for (int t = 0; t < NT; ++t) {
        if (t + 1 < NT) wait_vm4(); else wait_vm0();
        bar_raw();
        const float* Af = (const float*)(lds + (t & 1) * STR);
        const u16* Bs = (const u16*)(lds + (t & 1) * STR + ABYT);
        int gb = lane >> 4;
        f16x8 af[4]; s16x8 bf[4];
#pragma unroll
        for (int mi = 0; mi < 4; mi++) {
            int r = wr * 64 + mi * 16 + (lane & 15);
            int g0 = gb * 2;
            f32x4 lo4 = *(const f32x4*)&Af[r * 32 + ((g0 ^ r) & 7) * 4];
            f32x4 hi4 = *(const f32x4*)&Af[r * 32 + (((g0 + 1) ^ r) & 7) * 4];
            u32x4 pk;
            pk[0] = __builtin_bit_cast(unsigned, __builtin_amdgcn_cvt_pkrtz(lo4[0], lo4[1]));
            pk[1] = __builtin_bit_cast(unsigned, __builtin_amdgcn_cvt_pkrtz(lo4[2], lo4[3]));
            pk[2] = __builtin_bit_cast(unsigned, __builtin_amdgcn_cvt_pkrtz(hi4[0], hi4[1]));
            pk[3] = __builtin_bit_cast(unsigned, __builtin_amdgcn_cvt_pkrtz(hi4[2], hi4[3]));
            af[mi] = __builtin_bit_cast(f16x8, pk);
        }
#pragma unroll
        for (int ni = 0; ni < 4; ni++) {
            int r = wc * 64 + ni * 16 + (lane & 15);
            bf[ni] = *(const s16x8*)&Bs[r * 32 + ((gb ^ (r >> 1)) & 3) * 8];
        }
#pragma unroll
        for (int mi = 0; mi < 4; mi++)
#pragma unroll
            for (int ni = 0; ni < 4; ni++)
                acc[mi][ni] = __builtin_amdgcn_mfma_f32_16x16x32_f16(
                    af[mi], __builtin_bit_cast(f16x8, bf[ni]), acc[mi][ni], 0, 0, 0);
        bar_raw();
        if (t + 2 < NT) stage(t + 2, t & 1);
    }
    float* Outz = Out + (size_t)z * M * N;
    float bvv[4];
#pragma unroll
    for (int ni = 0; ni < 4; ni++)
        bvv[ni] = (SPLITK > 1) ? 0.f : bias[n0 + wc * 64 + ni * 16 + (lane & 15)];
#pragma unroll
    for (int mi = 0; mi < 4; mi++) {
        int rb = m0 + wr * 64 + mi * 16 + (lane >> 4) * 4;
#pragma unroll
        for (int j = 0; j < 4; j++) {
            size_t rowo = (size_t)(rb + j) * N;
#pragma unroll
            for (int ni = 0; ni < 4; ni++) {
                int col = n0 + wc * 64 + ni * 16 + (lane & 15);
                float x = acc[mi][ni][j] * (1.0f / 256.0f);
                if (SPLITK > 1) {
                    __builtin_nontemporal_store(x, &Outz[rowo + col]);
                } else {
                    x += bvv[ni];
                    Out[rowo + col] = x > 0.f ? x : 0.f;
                }
            }
        }
    }
}

// ---------------- GEMM2: 64x128 bf16, relu -> bf16, CM=8 chunked (R8-proven) ----------------
__global__ __launch_bounds__(256) void gemm2_k(const u16* __restrict__ A,
                                               const u16* __restrict__ BT,
                                               const float* __restrict__ bias,
                                               u16* __restrict__ Out,
                                               int M, int N, int K) {
    __shared__ __align__(16) u16 As[64][64];
    __shared__ __align__(16) u16 Bs[128][64];
    int tid = threadIdx.x, lane = tid & 63, wid = tid >> 6;
    int wr = wid >> 1, wc = wid & 1;
    int lin = blockIdx.x + gridDim.x * blockIdx.y;
    int nwg = gridDim.x * gridDim.y;
    int q = nwg >> 3;
    int logical = (lin & 7) * q + (lin >> 3);
    int Ny = N >> 7;
    int chunk = logical / (8 * Ny);
    int r2 = logical - chunk * (8 * Ny);
    int nb = r2 >> 3, mb = chunk * 8 + (r2 & 7);
    int m0 = mb << 6, n0 = nb << 7;
    f32x4 acc[2][4] = {};
    int NT = K >> 6;
    for (int t = 0; t < NT; ++t) {
        int k0 = t << 6;
#pragma unroll
        for (int i = 0; i < 2; i++) {
            int s = i * 256 + tid;
            int r = s >> 3, g = s & 7;
            int gs = (g ^ r) & 7;
            gload16(A + (size_t)(m0 + r) * K + k0 + gs * 8, &As[r][g * 8]);
        }
#pragma unroll
        for (int i = 0; i < 4; i++) {
            int s = i * 256 + tid;
            int r = s >> 3, g = s & 7;
            int gs = (g ^ r) & 7;
            gload16(BT + (size_t)(n0 + r) * K + k0 + gs * 8, &Bs[r][g * 8]);
        }
        __syncthreads();
#pragma unroll
        for (int kk = 0; kk < 2; kk++) {
            int gb = kk * 4 + (lane >> 4);
            s16x8 af[2], bf[4];
#pragma unroll
            for (int mi = 0; mi < 2; mi++) {
                int r = wr * 32 + mi * 16 + (lane & 15);
                af[mi] = *(const s16x8*)&As[r][((gb ^ r) & 7) * 8];
            }
#pragma unroll
            for (int ni = 0; ni < 4; ni++) {
                int r = wc * 64 + ni * 16 + (lane & 15);
                bf[ni] = *(const s16x8*)&Bs[r][((gb ^ r) & 7) * 8];
            }
#pragma unroll
            for (int mi = 0; mi < 2; mi++)
#pragma unroll
                for (int ni = 0; ni < 4; ni++)
                    acc[mi][ni] = __builtin_amdgcn_mfma_f32_16x16x32_bf16(
                        __builtin_bit_cast(bf16x8, af[mi]), __builtin_bit_cast(bf16x8, bf[ni]),
                        acc[mi][ni], 0, 0, 0);
        }
        __syncthreads();
    }
#pragma unroll
    for (int mi = 0; mi < 2; mi++) {
        int rb = m0 + wr * 32 + mi * 16 + (lane >> 4) * 4;
#pragma unroll
        for (int j = 0; j < 4; j++) {
            size_t rowo = (size_t)(rb + j) * N;
#pragma unroll
            for (int ni = 0; ni < 4; ni++) {
                int col = n0 + wc * 64 + ni * 16 + (lane & 15);
                float x = acc[mi][ni][j] + bias[col];
                Out[rowo + col] = f2bf_rn(x > 0.f ? x : 0.f);
            }
        }
    }
}

// ---------------- GEMM3: 256x256 bf16, 8 waves, K_STEP=32, 2-buf 64KB, R12 schedule ----------------
__global__ __launch_bounds__(512) void gemm3_k(const u16* __restrict__ A,
                                               const u16* __restrict__ BT,
                                               const float* __restrict__ bias,
                                               float* __restrict__ Out,
                                               int M, int N, int K) {
    constexpr int ABYT = 256 * 32 * 2;   // 16 KB
    constexpr int STR = 2 * ABYT;        // 32 KB
    __shared__ __align__(16) char lds[2 * STR];   // 64 KB -> 2 blocks/CU
    int tid = threadIdx.x, lane = tid & 63, wid = tid >> 6;
    int wr = wid >> 2, wc = wid & 3;     // 2 x 4 waves
    int lin = blockIdx.x + gridDim.x * blockIdx.y;
    int nwg = gridDim.x * gridDim.y;
    int q = nwg >> 3;
    int logical = (lin & 7) * q + (lin >> 3);
    int Ny = N >> 8;
    int chunk = logical / (2 * Ny);
    int r2 = logical - chunk * (2 * Ny);
    int nb = r2 >> 1, mb = chunk * 2 + (r2 & 1);
    int m0 = mb << 8, n0 = nb << 8;
    int NT = K >> 5;

    auto stage = [&](int t, int c) {
        int k0 = t << 5;
        char* bA = lds + c * STR;
        char* bB = bA + ABYT;
#pragma unroll
        for (int i = 0; i < 2; i++) {
            int s = i * 512 + tid;
            int r = s >> 2, g = s & 3;
            int gs = (g ^ (r >> 1)) & 3;
            gload16(A + (size_t)(m0 + r) * K + k0 + gs * 8, bA + r * 64 + g * 16);
        }
#pragma unroll
        for (int i = 0; i < 2; i++) {
            int s = i * 512 + tid;
            int r = s >> 2, g = s & 3;
            int gs = (g ^ (r >> 1)) & 3;
            gload16(BT + (size_t)(n0 + r) * K + k0 + gs * 8, bB + r * 64 + g * 16);
        }
    };

    f32x4 acc[8][4] = {};
    stage(0, 0);
    if (NT > 1) stage(1, 1);
    for (int t = 0; t < NT; ++t) {
        if (t + 1 < NT) wait_vm4(); else wait_vm0();
        bar_raw();
        const u16* As = (const u16*)(lds + (t & 1) * STR);
        const u16* Bs = (const u16*)(lds + (t & 1) * STR + ABYT);
        int gb = lane >> 4;
        s16x8 af[8], bf[4];
#pragma unroll
        for (int mi = 0; mi < 8; mi++) {
            int r = wr * 128 + mi * 16 + (lane & 15);
            af[mi] = *(const s16x8*)&As[r * 32 + ((gb ^ (r >> 1)) & 3) * 8];
        }
#pragma unroll
        for (int ni = 0; ni < 4; ni++) {
            int r = wc * 64 + ni * 16 + (lane & 15);
            bf[ni] = *(const s16x8*)&Bs[r * 32 + ((gb ^ (r >> 1)) & 3) * 8];
        }
#pragma unroll
        for (int mi = 0; mi < 8; mi++)
#pragma unroll
            for (int ni = 0; ni < 4; ni++)
                acc[mi][ni] = __builtin_amdgcn_mfma_f32_16x16x32_bf16(
                    __builtin_bit_cast(bf16x8, af[mi]), __builtin_bit_cast(bf16x8, bf[ni]),
                    acc[mi][ni], 0, 0, 0);
        bar_raw();
        if (t + 2 < NT) stage(t + 2, t & 1);
    }
    float bvv[4];
#pragma unroll
    for (int ni = 0; ni < 4; ni++) bvv[ni] = bias[n0 + wc * 64 + ni * 16 + (lane & 15)];
#pragma unroll
    for (int mi = 0; mi < 8; mi++) {
        int rb = m0 + wr * 128 + mi * 16 + (lane >> 4) * 4;
#pragma unroll
        for (int j = 0; j < 4; j++) {
            size_t rowo = (size_t)(rb + j) * N;
#pragma unroll
            for (int ni = 0; ni < 4; ni++) {
                int col = n0 + wc * 64 + ni * 16 + (lane & 15);
                float x = acc[mi][ni][j] + bvv[ni];
                __builtin_nontemporal_store(1.f / (1.f + __expf(-x)), &Out[rowo + col]);
            }
        }
    }
}

// ---------------- fused split-K reduce + top-64 threshold ----------------
template <int NZ>
__global__ __launch_bounds__(256) void topk_kernel(float* __restrict__ P,
                                                   const float* __restrict__ bias,
                                                   u16* __restrict__ HM,
                                                   float* __restrict__ rowT,
                                                   unsigned* __restrict__ rowFlag,
                                                   int MN) {
    int row = blockIdx.x * 4 + (threadIdx.x >> 6);
    int lane = threadIdx.x & 63;
    float* hr = P + (size_t)row * 1024;
    float v[16];
    if (NZ > 0) {
#pragma unroll
        for (int i = 0; i < 4; i++) {
            f32x4 a = *(const f32x4*)(hr + lane * 16 + i * 4);
            for (int zz = 1; zz < NZ; zz++)
                a += *(const f32x4*)(hr + (size_t)zz * MN + lane * 16 + i * 4);
            f32x4 b = *(const f32x4*)(bias + lane * 16 + i * 4);
            a += b;
#pragma unroll
            for (int j = 0; j < 4; j++) a[j] = a[j] > 0.f ? a[j] : 0.f;
            *(f32x4*)&v[i * 4] = a;
            *(f32x4*)(hr + lane * 16 + i * 4) = a;   // reduced H for fixup
        }
    } else {
#pragma unroll
        for (int i = 0; i < 4; i++) *(f32x4*)&v[i * 4] = *(const f32x4*)(hr + lane * 16 + i * 4);
    }
    unsigned u[16];
#pragma unroll
    for (int i = 0; i < 16; i++) u[i] = __float_as_uint(v[i]);
    unsigned lo = 0;
    for (int b = 30; b >= 0; --b) {
        unsigned cand = lo | (1u << b);
        int c = 0;
#pragma unroll
        for (int i = 0; i < 16; i++) c += (u[i] >= cand);
#pragma unroll
        for (int off = 32; off; off >>= 1) c += __shfl_xor(c, off);
        if (c >= 64) lo = cand;
    }
    unsigned m2 = 0;
#pragma unroll
    for (int i = 0; i < 16; i++)
        if (u[i] < lo && u[i] > m2) m2 = u[i];
#pragma unroll
    for (int off = 32; off; off >>= 1) {
        unsigned o = __shfl_xor(m2, off);
        if (o > m2) m2 = o;
    }
    u16 o16[16];
#pragma unroll
    for (int i = 0; i < 16; i++) o16[i] = (u[i] >= lo) ? f2bf_rn(v[i]) : (u16)0;
    unsigned p[8];
#pragma unroll
    for (int i = 0; i < 8; i++) p[i] = (unsigned)o16[2 * i] | ((unsigned)o16[2 * i + 1] << 16);
    u16* dst = HM + (size_t)row * 1024 + lane * 16;
    *(uint4*)dst = make_uint4(p[0], p[1], p[2], p[3]);
    *(uint4*)(dst + 8) = make_uint4(p[4], p[5], p[6], p[7]);
    if (lane == 0) {
        rowT[row] = __uint_as_float(lo);
        float t = __uint_as_float(lo), s = __uint_as_float(m2);
        rowFlag[row] = (lo != 0u) && (t - s < SEL_BAND);
    }
}

// ---------------- fp64 fix-up: 256 thr, wave-per-candidate, 4-chain dots ----------------
__global__ __launch_bounds__(256) void fixup_kernel(const float* __restrict__ H,
                                                    const float* __restrict__ X,
                                                    const float* __restrict__ W,  // [1024][12288] f32 (We1^T)
                                                    const float* __restrict__ be1,
                                                    const float* __restrict__ rowT,
                                                    const unsigned* __restrict__ rowFlag,
                                                    u16* __restrict__ HM) {
    int row = blockIdx.x;
    if (!rowFlag[row]) return;
    int tid = threadIdx.x, lane = tid & 63, wv = tid >> 6;
    float Tf = rowT[row];
    const float* hr = H + (size_t)row * 1024;
    f32x4 v = *(const f32x4*)(hr + tid * 4);
    __shared__ int bidx[64];
    __shared__ float bval[64];
    __shared__ double dval[64];
    __shared__ int cnt, csh;
    if (tid == 0) { cnt = 0; csh = 0; }
    __syncthreads();
    int myS = 0;
#pragma unroll
    for (int i = 0; i < 4; i++) {
        float x = v[i];
        if (fabsf(x - Tf) <= SEL_BAND) {
            int p = atomicAdd(&cnt, 1);
            if (p < 64) { bidx[p] = tid * 4 + i; bval[p] = x; }
        }
        myS += (x > Tf + SEL_BAND);
    }
#pragma unroll
    for (int off = 32; off; off >>= 1) myS += __shfl_xor(myS, off);
    if (lane == 0) atomicAdd(&csh, myS);
    __syncthreads();
    int nb = cnt < 64 ? cnt : 64;
    if (nb < 2) return;
    int kband = 64 - csh;
    const float* xr = X + (size_t)row * 12288;
    for (int e = wv; e < nb; e += 4) {
        const float* wp = W + (size_t)bidx[e] * 12288;
        double s0 = 0, s1 = 0, s2 = 0, s3 = 0;
        for (int k0 = 0; k0 < 12288; k0 += 256) {
            s0 += (double)xr[k0 + lane]       * (double)wp[k0 + lane];
            s1 += (double)xr[k0 + 64 + lane]  * (double)wp[k0 + 64 + lane];
            s2 += (double)xr[k0 + 128 + lane] * (double)wp[k0 + 128 + lane];
            s3 += (double)xr[k0 + 192 + lane] * (double)wp[k0 + 192 + lane];
        }
        double s = (s0 + s1) + (s2 + s3);
#pragma unroll
        for (int off = 32; off; off >>= 1) s += __shfl_xor(s, off);
        if (lane == 0) dval[e] = s + (double)be1[bidx[e]];
    }
    __syncthreads();
    if (tid < nb) {
        double me = dval[tid];
        int j = bidx[tid];
        int rank = 0;
        for (int f = 0; f < nb; f++) {
            double df = dval[f];
            rank += (df > me) || (df == me && bidx[f] < j);
        }
        HM[(size_t)row * 1024 + j] = (rank < kband) ? f2bf_rn(bval[tid]) : (u16)0;
    }
}

extern "C" void kernel_launch(void* const* d_in, const int* in_sizes, int n_in,
                              void* d_out, int out_size, void* d_ws, size_t ws_size,
                              hipStream_t stream) {
    const float* X   = (const float*)d_in[0];
    const float* We1 = (const float*)d_in[1];
    const float* be1 = (const float*)d_in[2];
    const float* Wd1 = (const float*)d_in[3];
    const float* bd1 = (const float*)d_in[4];
    const float* Wd2 = (const float*)d_in[5];
    const float* bd2 = (const float*)d_in[6];

    // workspace tiers: base 136.3 MB (proven) + (SPLITK-1) x 16.8 MB partials
    int splitk = (ws_size >= 187100000ull) ? 4 : (ws_size >= 153600000ull) ? 2 : 1;

    char* ws = (char*)d_ws;
    size_t off = 0;
    auto alloc = [&](size_t bytes) { void* p = ws + off; off += (bytes + 255) & ~(size_t)255; return p; };
    u16* W1hT    = (u16*)alloc(12288ull * 1024 * 2);   // fp16 bits x256, [1024][12288]
    float* We1Tf = (float*)alloc(12288ull * 1024 * 4); // f32 [1024][12288] for fixup
    u16* Wd1T    = (u16*)alloc(1024ull * 1024 * 2);
    u16* Wd2T    = (u16*)alloc(1024ull * 12288 * 2);
    float* Hbuf  = (float*)alloc((size_t)splitk * 4096 * 1024 * 4);  // partial[0] == Hbuf
    u16* HM      = (u16*)alloc(4096ull * 1024 * 2);
    u16* Dbf     = (u16*)alloc(4096ull * 1024 * 2);
    float* rowT  = (float*)alloc(4096 * 4);
    unsigned* rowFlag = (unsigned*)alloc(4096 * 4);

    dim3 tb(32, 8);
    tr_hf<<<dim3(32, 384), tb, 0, stream>>>(We1, 12288, 1024, W1hT, We1Tf);
    tr_bf16<<<dim3(32, 32), tb, 0, stream>>>(Wd1, 1024, 1024, Wd1T);
    tr_bf16<<<dim3(384, 32), tb, 0, stream>>>(Wd2, 1024, 12288, Wd2T);

    if (splitk == 4) {
        gemm1_k<4><<<dim3(32, 4, 4), 512, 0, stream>>>(X, W1hT, be1, Hbuf, 4096, 1024, 12288);
        topk_kernel<4><<<1024, 256, 0, stream>>>(Hbuf, be1, HM, rowT, rowFlag, 4096 * 1024);
    } else if (splitk == 2) {
        gemm1_k<2><<<dim3(32, 4, 2), 512, 0, stream>>>(X, W1hT, be1, Hbuf, 4096, 1024, 12288);
        topk_kernel<2><<<1024, 256, 0, stream>>>(Hbuf, be1, HM, rowT, rowFlag, 4096 * 1024);
    } else {
        gemm1_k<1><<<dim3(32, 4), 512, 0, stream>>>(X, W1hT, be1, Hbuf, 4096, 1024, 12288);
        topk_kernel<0><<<1024, 256, 0, stream>>>(Hbuf, be1, HM, rowT, rowFlag, 4096 * 1024);
    }
    fixup_kernel<<<4096, 256, 0, stream>>>(Hbuf, X, We1Tf, be1, rowT, rowFlag, HM);
    gemm2_k<<<dim3(64, 8), 256, 0, stream>>>(HM, Wd1T, bd1, Dbf, 4096, 1024, 1024);
    gemm3_k<<<dim3(16, 48), 512, 0, stream>>>(Dbf, Wd2T, bd2, (float*)d_out, 4096, 12288, 1024);
}

// Round 16
// 532.049 us; speedup vs baseline: 1.0363x; 1.0363x over previous
//
#include <hip/hip_runtime.h>

typedef float f32x4 __attribute__((ext_vector_type(4)));
typedef __bf16 bf16x8 __attribute__((ext_vector_type(8)));
typedef _Float16 f16x8 __attribute__((ext_vector_type(8)));
typedef short s16x8 __attribute__((ext_vector_type(8)));
typedef unsigned int u32x4 __attribute__((ext_vector_type(4)));
typedef unsigned short u16;

#define DEV static __device__ __forceinline__

#define SEL_BAND 1.2e-3f   // ~7.7 sigma of fp16-GEMM1 error; fp64 re-rank inside band

DEV u16 f2bf_rn(float f) {
    unsigned u = __float_as_uint(f);
    return (u16)((u + 0x7fffu + ((u >> 16) & 1u)) >> 16);
}

typedef __attribute__((address_space(3))) unsigned int lds_u32;
typedef __attribute__((address_space(1))) const unsigned int glb_u32;

DEV void gload16(const void* g, void* l) {
    __builtin_amdgcn_global_load_lds((glb_u32*)g, (lds_u32*)l, 16, 0, 0);
}
DEV void bar_raw() { asm volatile("s_barrier" ::: "memory"); }
DEV void wait_vm8() { asm volatile("s_waitcnt vmcnt(8)" ::: "memory"); }
DEV void wait_vm0() { asm volatile("s_waitcnt vmcnt(0)" ::: "memory"); }

// ---------------- transpose [R][C] f32 -> [C][R] fp16*256 + f32 ----------------
__global__ __launch_bounds__(256) void tr_hf(const float* __restrict__ src, int R, int C,
                                             u16* __restrict__ hT, float* __restrict__ fT) {
    __shared__ float t[32][33];
    int tx = threadIdx.x, ty = threadIdx.y;
    int c0 = blockIdx.x * 32, r0 = blockIdx.y * 32;
#pragma unroll
    for (int i = 0; i < 4; i++) t[ty + i * 8][tx] = src[(size_t)(r0 + ty + i * 8) * C + c0 + tx];
    __syncthreads();
#pragma unroll
    for (int i = 0; i < 4; i++) {
        int c = c0 + ty + i * 8;
        float v = t[tx][ty + i * 8];
        size_t o = (size_t)c * R + r0 + tx;
        hT[o] = __builtin_bit_cast(u16, (_Float16)(v * 256.0f));
        fT[o] = v;
    }
}

// ---------------- transpose [R][C] f32 -> [C][R] bf16 ----------------
__global__ __launch_bounds__(256) void tr_bf16(const float* __restrict__ src, int R, int C,
                                               u16* __restrict__ dst) {
    __shared__ float t[32][33];
    int tx = threadIdx.x, ty = threadIdx.y;
    int c0 = blockIdx.x * 32, r0 = blockIdx.y * 32;
#pragma unroll
    for (int i = 0; i < 4; i++) t[ty + i * 8][tx] = src[(size_t)(r0 + ty + i * 8) * C + c0 + tx];
    __syncthreads();
#pragma unroll
    for (int i = 0; i < 4; i++)
        dst[(size_t)(c0 + ty + i * 8) * R + r0 + tx] = f2bf_rn(t[tx][ty + i * 8]);
}

// ---------------- GEMM1: 128x256, 8 waves, split-K, K_STEP=64, dbuf + counted vmcnt (R12-proven) ----------------
template <int SPLITK>
__global__ __launch_bounds__(512) void gemm1_k(const float* __restrict__ A,
                                               const u16* __restrict__ BT,
                                               const float* __restrict__ bias,
                                               float* __restrict__ Out,
                                               int M, int N, int K) {
    constexpr int ABYT = 128 * 64 * 4;   // 32 KB f32
    constexpr int BBYT = 256 * 64 * 2;   // 32 KB f16 bits
    __shared__ __align__(16) char lds[2][ABYT + BBYT];
    int tid = threadIdx.x, lane = tid & 63, wid = tid >> 6;
    int wr = wid >> 2, wc = wid & 3;    // 2 x 4 waves, WM=64, WN=64

    int lin = blockIdx.x + gridDim.x * (blockIdx.y + gridDim.y * blockIdx.z);
    int nwg = gridDim.x * gridDim.y * gridDim.z;
    int q = nwg >> 3;
    int logical = (lin & 7) * q + (lin >> 3);
    int Ny = N >> 8, Mx = M >> 7;
    int per = Mx * Ny;
    int z = logical / per;
    int rem = logical - z * per;
    int mb = rem / Ny, nb = rem - mb * Ny;   // nb fastest
    int m0 = mb << 7, n0 = nb << 8;
    int Ksl = K / SPLITK;
    int kbase = z * Ksl;
    int NT = Ksl >> 6;

    auto stage = [&](int t, int c) {
        int k0 = kbase + (t << 6);
        char* bA = lds[c];
        char* bB = lds[c] + ABYT;
#pragma unroll
        for (int i = 0; i < 4; i++) {    // A: 128 rows x 16 f32-granules
            int s = i * 512 + tid;
            int r = s >> 4, g = s & 15;
            int gs = (g & 8) | ((g ^ r) & 7);
            gload16(A + (size_t)(m0 + r) * K + k0 + gs * 4, bA + r * 256 + g * 16);
        }
#pragma unroll
        for (int i = 0; i < 4; i++) {    // B: 256 rows x 8 half-granules
            int s = i * 512 + tid;
            int r = s >> 3, g = s & 7;
            int gs = (g ^ r) & 7;
            gload16(BT + (size_t)(n0 + r) * K + k0 + gs * 8, bB + r * 128 + g * 16);
        }
    };

    f32x4 acc[4][4] = {};
    stage(0, 0);
    if (NT > 1) stage(1, 1);
    for (int t = 0; t < NT; ++t) {
        if (t + 1 < NT) wait_vm8(); else wait_vm0();
        bar_raw();
        const float* Af = (const float*)lds[t & 1];
        const u16* Bs = (const u16*)(lds[t & 1] + ABYT);
#pragma unroll
        for (int kk = 0; kk < 2; kk++) {
            int gb = kk * 4 + (lane >> 4);
            f16x8 af[4]; s16x8 bf[4];
#pragma unroll
            for (int mi = 0; mi < 4; mi++) {
                int r = wr * 64 + mi * 16 + (lane & 15);
                int ra = r & 7;
                int g0 = gb * 2;
                f32x4 lo4 = *(const f32x4*)&Af[r * 64 + (((g0 ^ ra) & 7) | (g0 & 8)) * 4];
                f32x4 hi4 = *(const f32x4*)&Af[r * 64 + ((((g0 + 1) ^ ra) & 7) | ((g0 + 1) & 8)) * 4];
                u32x4 pk;
                pk[0] = __builtin_bit_cast(unsigned, __builtin_amdgcn_cvt_pkrtz(lo4[0], lo4[1]));
                pk[1] = __builtin_bit_cast(unsigned, __builtin_amdgcn_cvt_pkrtz(lo4[2], lo4[3]));
                pk[2] = __builtin_bit_cast(unsigned, __builtin_amdgcn_cvt_pkrtz(hi4[0], hi4[1]));
                pk[3] = __builtin_bit_cast(unsigned, __builtin_amdgcn_cvt_pkrtz(hi4[2], hi4[3]));
                af[mi] = __builtin_bit_cast(f16x8, pk);
            }
#pragma unroll
            for (int ni = 0; ni < 4; ni++) {
                int r = wc * 64 + ni * 16 + (lane & 15);
                bf[ni] = *(const s16x8*)&Bs[r * 64 + ((gb ^ r) & 7) * 8];
            }
#pragma unroll
            for (int mi = 0; mi < 4; mi++)
#pragma unroll
                for (int ni = 0; ni < 4; ni++)
                    acc[mi][ni] = __builtin_amdgcn_mfma_f32_16x16x32_f16(
                        af[mi], __builtin_bit_cast(f16x8, bf[ni]), acc[mi][ni], 0, 0, 0);
        }
        bar_raw();
        if (t + 2 < NT) stage(t + 2, t & 1);
    }
    float* Outz = Out + (size_t)z * M * N;
    float bvv[4];
#pragma unroll
    for (int ni = 0; ni < 4; ni++)
        bvv[ni] = (SPLITK > 1) ? 0.f : bias[n0 + wc * 64 + ni * 16 + (lane & 15)];
#pragma unroll
    for (int mi = 0; mi < 4; mi++) {
        int rb = m0 + wr * 64 + mi * 16 + (lane >> 4) * 4;
#pragma unroll
        for (int j = 0; j < 4; j++) {
            size_t rowo = (size_t)(rb + j) * N;
#pragma unroll
            for (int ni = 0; ni < 4; ni++) {
                int col = n0 + wc * 64 + ni * 16 + (lane & 15);
                float x = acc[mi][ni][j] * (1.0f / 256.0f);
                if (SPLITK > 1) {
                    __builtin_nontemporal_store(x, &Outz[rowo + col]);
                } else {
                    x += bvv[ni];
                    Out[rowo + col] = x > 0.f ? x : 0.f;
                }
            }
        }
    }
}

// ---------------- GEMM2: 64x128 bf16, relu -> bf16, CM=8 chunked (R8-proven) ----------------
__global__ __launch_bounds__(256) void gemm2_k(const u16* __restrict__ A,
                                               const u16* __restrict__ BT,
                                               const float* __restrict__ bias,
                                               u16* __restrict__ Out,
                                               int M, int N, int K) {
    __shared__ __align__(16) u16 As[64][64];
    __shared__ __align__(16) u16 Bs[128][64];
    int tid = threadIdx.x, lane = tid & 63, wid = tid >> 6;
    int wr = wid >> 1, wc = wid & 1;
    int lin = blockIdx.x + gridDim.x * blockIdx.y;
    int nwg = gridDim.x * gridDim.y;
    int q = nwg >> 3;
    int logical = (lin & 7) * q + (lin >> 3);
    int Ny = N >> 7;
    int chunk = logical / (8 * Ny);
    int r2 = logical - chunk * (8 * Ny);
    int nb = r2 >> 3, mb = chunk * 8 + (r2 & 7);
    int m0 = mb << 6, n0 = nb << 7;
    f32x4 acc[2][4] = {};
    int NT = K >> 6;
    for (int t = 0; t < NT; ++t) {
        int k0 = t << 6;
#pragma unroll
        for (int i = 0; i < 2; i++) {
            int s = i * 256 + tid;
            int r = s >> 3, g = s & 7;
            int gs = (g ^ r) & 7;
            gload16(A + (size_t)(m0 + r) * K + k0 + gs * 8, &As[r][g * 8]);
        }
#pragma unroll
        for (int i = 0; i < 4; i++) {
            int s = i * 256 + tid;
            int r = s >> 3, g = s & 7;
            int gs = (g ^ r) & 7;
            gload16(BT + (size_t)(n0 + r) * K + k0 + gs * 8, &Bs[r][g * 8]);
        }
        __syncthreads();
#pragma unroll
        for (int kk = 0; kk < 2; kk++) {
            int gb = kk * 4 + (lane >> 4);
            s16x8 af[2], bf[4];
#pragma unroll
            for (int mi = 0; mi < 2; mi++) {
                int r = wr * 32 + mi * 16 + (lane & 15);
                af[mi] = *(const s16x8*)&As[r][((gb ^ r) & 7) * 8];
            }
#pragma unroll
            for (int ni = 0; ni < 4; ni++) {
                int r = wc * 64 + ni * 16 + (lane & 15);
                bf[ni] = *(const s16x8*)&Bs[r][((gb ^ r) & 7) * 8];
            }
#pragma unroll
            for (int mi = 0; mi < 2; mi++)
#pragma unroll
                for (int ni = 0; ni < 4; ni++)
                    acc[mi][ni] = __builtin_amdgcn_mfma_f32_16x16x32_bf16(
                        __builtin_bit_cast(bf16x8, af[mi]), __builtin_bit_cast(bf16x8, bf[ni]),
                        acc[mi][ni], 0, 0, 0);
        }
        __syncthreads();
    }
#pragma unroll
    for (int mi = 0; mi < 2; mi++) {
        int rb = m0 + wr * 32 + mi * 16 + (lane >> 4) * 4;
#pragma unroll
        for (int j = 0; j < 4; j++) {
            size_t rowo = (size_t)(rb + j) * N;
#pragma unroll
            for (int ni = 0; ni < 4; ni++) {
                int col = n0 + wc * 64 + ni * 16 + (lane & 15);
                float x = acc[mi][ni][j] + bias[col];
                Out[rowo + col] = f2bf_rn(x > 0.f ? x : 0.f);
            }
        }
    }
}

// ---------------- GEMM3: 256x256 bf16, 8 waves, K_STEP=64, dbuf + counted vmcnt, CM=2 chunk (R12-proven) ----------------
__global__ __launch_bounds__(512) void gemm3_k(const u16* __restrict__ A,
                                               const u16* __restrict__ BT,
                                               const float* __restrict__ bias,
                                               float* __restrict__ Out,
                                               int M, int N, int K) {
    constexpr int ABYT = 256 * 64 * 2;   // 32 KB
    __shared__ __align__(16) char lds[2][2 * ABYT];
    int tid = threadIdx.x, lane = tid & 63, wid = tid >> 6;
    int wr = wid >> 2, wc = wid & 3;     // 2 x 4 waves
    int lin = blockIdx.x + gridDim.x * blockIdx.y;
    int nwg = gridDim.x * gridDim.y;
    int q = nwg >> 3;
    int logical = (lin & 7) * q + (lin >> 3);
    int Ny = N >> 8;
    int chunk = logical / (2 * Ny);
    int r2 = logical - chunk * (2 * Ny);
    int nb = r2 >> 1, mb = chunk * 2 + (r2 & 1);
    int m0 = mb << 8, n0 = nb << 8;
    int NT = K >> 6;

    auto stage = [&](int t, int c) {
        int k0 = t << 6;
        u16* As = (u16*)lds[c];
        u16* Bs = (u16*)(lds[c] + ABYT);
#pragma unroll
        for (int i = 0; i < 4; i++) {
            int s = i * 512 + tid;
            int r = s >> 3, g = s & 7;
            int gs = (g ^ r) & 7;
            gload16(A + (size_t)(m0 + r) * K + k0 + gs * 8, As + r * 64 + g * 8);
        }
#pragma unroll
        for (int i = 0; i < 4; i++) {
            int s = i * 512 + tid;
            int r = s >> 3, g = s & 7;
            int gs = (g ^ r) & 7;
            gload16(BT + (size_t)(n0 + r) * K + k0 + gs * 8, Bs + r * 64 + g * 8);
        }
    };

    f32x4 acc[8][4] = {};
    stage(0, 0);
    if (NT > 1) stage(1, 1);
    for (int t = 0; t < NT; ++t) {
        if (t + 1 < NT) wait_vm8(); else wait_vm0();
        bar_raw();
        const u16* As = (const u16*)lds[t & 1];
        const u16* Bs = (const u16*)(lds[t & 1] + ABYT);
#pragma unroll
        for (int kk = 0; kk < 2; kk++) {
            int gb = kk * 4 + (lane >> 4);
            s16x8 af[8], bf[4];
#pragma unroll
            for (int mi = 0; mi < 8; mi++) {
                int r = wr * 128 + mi * 16 + (lane & 15);
                af[mi] = *(const s16x8*)&As[r * 64 + ((gb ^ r) & 7) * 8];
            }
#pragma unroll
            for (int ni = 0; ni < 4; ni++) {
                int r = wc * 64 + ni * 16 + (lane & 15);
                bf[ni] = *(const s16x8*)&Bs[r * 64 + ((gb ^ r) & 7) * 8];
            }
#pragma unroll
            for (int mi = 0; mi < 8; mi++)
#pragma unroll
                for (int ni = 0; ni < 4; ni++)
                    acc[mi][ni] = __builtin_amdgcn_mfma_f32_16x16x32_bf16(
                        __builtin_bit_cast(bf16x8, af[mi]), __builtin_bit_cast(bf16x8, bf[ni]),
                        acc[mi][ni], 0, 0, 0);
        }
        bar_raw();
        if (t + 2 < NT) stage(t + 2, t & 1);
    }
    float bvv[4];
#pragma unroll
    for (int ni = 0; ni < 4; ni++) bvv[ni] = bias[n0 + wc * 64 + ni * 16 + (lane & 15)];
#pragma unroll
    for (int mi = 0; mi < 8; mi++) {
        int rb = m0 + wr * 128 + mi * 16 + (lane >> 4) * 4;
#pragma unroll
        for (int j = 0; j < 4; j++) {
            size_t rowo = (size_t)(rb + j) * N;
#pragma unroll
            for (int ni = 0; ni < 4; ni++) {
                int col = n0 + wc * 64 + ni * 16 + (lane & 15);
                float x = acc[mi][ni][j] + bvv[ni];
                __builtin_nontemporal_store(1.f / (1.f + __expf(-x)), &Out[rowo + col]);
            }
        }
    }
}

// ---------------- fused split-K reduce + top-64 threshold ----------------
template <int NZ>
__global__ __launch_bounds__(256) void topk_kernel(float* __restrict__ P,
                                                   const float* __restrict__ bias,
                                                   u16* __restrict__ HM,
                                                   float* __restrict__ rowT,
                                                   unsigned* __restrict__ rowFlag,
                                                   int MN) {
    int row = blockIdx.x * 4 + (threadIdx.x >> 6);
    int lane = threadIdx.x & 63;
    float* hr = P + (size_t)row * 1024;
    float v[16];
    if (NZ > 0) {
#pragma unroll
        for (int i = 0; i < 4; i++) {
            f32x4 a = *(const f32x4*)(hr + lane * 16 + i * 4);
            for (int zz = 1; zz < NZ; zz++)
                a += *(const f32x4*)(hr + (size_t)zz * MN + lane * 16 + i * 4);
            f32x4 b = *(const f32x4*)(bias + lane * 16 + i * 4);
            a += b;
#pragma unroll
            for (int j = 0; j < 4; j++) a[j] = a[j] > 0.f ? a[j] : 0.f;
            *(f32x4*)&v[i * 4] = a;
            *(f32x4*)(hr + lane * 16 + i * 4) = a;   // reduced H for fixup
        }
    } else {
#pragma unroll
        for (int i = 0; i < 4; i++) *(f32x4*)&v[i * 4] = *(const f32x4*)(hr + lane * 16 + i * 4);
    }
    unsigned u[16];
#pragma unroll
    for (int i = 0; i < 16; i++) u[i] = __float_as_uint(v[i]);
    unsigned lo = 0;
    for (int b = 30; b >= 0; --b) {
        unsigned cand = lo | (1u << b);
        int c = 0;
#pragma unroll
        for (int i = 0; i < 16; i++) c += (u[i] >= cand);
#pragma unroll
        for (int off = 32; off; off >>= 1) c += __shfl_xor(c, off);
        if (c >= 64) lo = cand;
    }
    unsigned m2 = 0;
#pragma unroll
    for (int i = 0; i < 16; i++)
        if (u[i] < lo && u[i] > m2) m2 = u[i];
#pragma unroll
    for (int off = 32; off; off >>= 1) {
        unsigned o = __shfl_xor(m2, off);
        if (o > m2) m2 = o;
    }
    u16 o16[16];
#pragma unroll
    for (int i = 0; i < 16; i++) o16[i] = (u[i] >= lo) ? f2bf_rn(v[i]) : (u16)0;
    unsigned p[8];
#pragma unroll
    for (int i = 0; i < 8; i++) p[i] = (unsigned)o16[2 * i] | ((unsigned)o16[2 * i + 1] << 16);
    u16* dst = HM + (size_t)row * 1024 + lane * 16;
    *(uint4*)dst = make_uint4(p[0], p[1], p[2], p[3]);
    *(uint4*)(dst + 8) = make_uint4(p[4], p[5], p[6], p[7]);
    if (lane == 0) {
        rowT[row] = __uint_as_float(lo);
        float t = __uint_as_float(lo), s = __uint_as_float(m2);
        rowFlag[row] = (lo != 0u) && (t - s < SEL_BAND);
    }
}

// ---------------- fp64 fix-up: 256 thr, wave-per-candidate, 4-chain dots ----------------
__global__ __launch_bounds__(256) void fixup_kernel(const float* __restrict__ H,
                                                    const float* __restrict__ X,
                                                    const float* __restrict__ W,  // [1024][12288] f32 (We1^T)
                                                    const float* __restrict__ be1,
                                                    const float* __restrict__ rowT,
                                                    const unsigned* __restrict__ rowFlag,
                                                    u16* __restrict__ HM) {
    int row = blockIdx.x;
    if (!rowFlag[row]) return;
    int tid = threadIdx.x, lane = tid & 63, wv = tid >> 6;
    float Tf = rowT[row];
    const float* hr = H + (size_t)row * 1024;
    f32x4 v = *(const f32x4*)(hr + tid * 4);
    __shared__ int bidx[64];
    __shared__ float bval[64];
    __shared__ double dval[64];
    __shared__ int cnt, csh;
    if (tid == 0) { cnt = 0; csh = 0; }
    __syncthreads();
    int myS = 0;
#pragma unroll
    for (int i = 0; i < 4; i++) {
        float x = v[i];
        if (fabsf(x - Tf) <= SEL_BAND) {
            int p = atomicAdd(&cnt, 1);
            if (p < 64) { bidx[p] = tid * 4 + i; bval[p] = x; }
        }
        myS += (x > Tf + SEL_BAND);
    }
#pragma unroll
    for (int off = 32; off; off >>= 1) myS += __shfl_xor(myS, off);
    if (lane == 0) atomicAdd(&csh, myS);
    __syncthreads();
    int nb = cnt < 64 ? cnt : 64;
    if (nb < 2) return;
    int kband = 64 - csh;
    const float* xr = X + (size_t)row * 12288;
    for (int e = wv; e < nb; e += 4) {
        const float* wp = W + (size_t)bidx[e] * 12288;
        double s0 = 0, s1 = 0, s2 = 0, s3 = 0;
        for (int k0 = 0; k0 < 12288; k0 += 256) {
            s0 += (double)xr[k0 + lane]       * (double)wp[k0 + lane];
            s1 += (double)xr[k0 + 64 + lane]  * (double)wp[k0 + 64 + lane];
            s2 += (double)xr[k0 + 128 + lane] * (double)wp[k0 + 128 + lane];
            s3 += (double)xr[k0 + 192 + lane] * (double)wp[k0 + 192 + lane];
        }
        double s = (s0 + s1) + (s2 + s3);
#pragma unroll
        for (int off = 32; off; off >>= 1) s += __shfl_xor(s, off);
        if (lane == 0) dval[e] = s + (double)be1[bidx[e]];
    }
    __syncthreads();
    if (tid < nb) {
        double me = dval[tid];
        int j = bidx[tid];
        int rank = 0;
        for (int f = 0; f < nb; f++) {
            double df = dval[f];
            rank += (df > me) || (df == me && bidx[f] < j);
        }
        HM[(size_t)row * 1024 + j] = (rank < kband) ? f2bf_rn(bval[tid]) : (u16)0;
    }
}

extern "C" void kernel_launch(void* const* d_in, const int* in_sizes, int n_in,
                              void* d_out, int out_size, void* d_ws, size_t ws_size,
                              hipStream_t stream) {
    const float* X   = (const float*)d_in[0];
    const float* We1 = (const float*)d_in[1];
    const float* be1 = (const float*)d_in[2];
    const float* Wd1 = (const float*)d_in[3];
    const float* bd1 = (const float*)d_in[4];
    const float* Wd2 = (const float*)d_in[5];
    const float* bd2 = (const float*)d_in[6];

    // workspace tiers: base 136.3 MB (proven) + (SPLITK-1) x 16.8 MB partials
    int splitk = (ws_size >= 187100000ull) ? 4 : (ws_size >= 153600000ull) ? 2 : 1;

    char* ws = (char*)d_ws;
    size_t off = 0;
    auto alloc = [&](size_t bytes) { void* p = ws + off; off += (bytes + 255) & ~(size_t)255; return p; };
    u16* W1hT    = (u16*)alloc(12288ull * 1024 * 2);   // fp16 bits x256, [1024][12288]
    float* We1Tf = (float*)alloc(12288ull * 1024 * 4); // f32 [1024][12288] for fixup
    u16* Wd1T    = (u16*)alloc(1024ull * 1024 * 2);
    u16* Wd2T    = (u16*)alloc(1024ull * 12288 * 2);
    float* Hbuf  = (float*)alloc((size_t)splitk * 4096 * 1024 * 4);  // partial[0] == Hbuf
    u16* HM      = (u16*)alloc(4096ull * 1024 * 2);
    u16* Dbf     = (u16*)alloc(4096ull * 1024 * 2);
    float* rowT  = (float*)alloc(4096 * 4);
    unsigned* rowFlag = (unsigned*)alloc(4096 * 4);

    dim3 tb(32, 8);
    tr_hf<<<dim3(32, 384), tb, 0, stream>>>(We1, 12288, 1024, W1hT, We1Tf);
    tr_bf16<<<dim3(32, 32), tb, 0, stream>>>(Wd1, 1024, 1024, Wd1T);
    tr_bf16<<<dim3(384, 32), tb, 0, stream>>>(Wd2, 1024, 12288, Wd2T);

    if (splitk == 4) {
        gemm1_k<4><<<dim3(32, 4, 4), 512, 0, stream>>>(X, W1hT, be1, Hbuf, 4096, 1024, 12288);
        topk_kernel<4><<<1024, 256, 0, stream>>>(Hbuf, be1, HM, rowT, rowFlag, 4096 * 1024);
    } else if (splitk == 2) {
        gemm1_k<2><<<dim3(32, 4, 2), 512, 0, stream>>>(X, W1hT, be1, Hbuf, 4096, 1024, 12288);
        topk_kernel<2><<<1024, 256, 0, stream>>>(Hbuf, be1, HM, rowT, rowFlag, 4096 * 1024);
    } else {
        gemm1_k<1><<<dim3(32, 4), 512, 0, stream>>>(X, W1hT, be1, Hbuf, 4096, 1024, 12288);
        topk_kernel<0><<<1024, 256, 0, stream>>>(Hbuf, be1, HM, rowT, rowFlag, 4096 * 1024);
    }
    fixup_kernel<<<4096, 256, 0, stream>>>(Hbuf, X, We1Tf, be1, rowT, rowFlag, HM);
    gemm2_k<<<dim3(64, 8), 256, 0, stream>>>(HM, Wd1T, bd1, Dbf, 4096, 1024, 1024);
    gemm3_k<<<dim3(16, 48), 512, 0, stream>>>(Dbf, Wd2T, bd2, (float*)d_out, 4096, 12288, 1024);
}